// Round 20
// baseline (453.856 us; speedup 1.0000x reference)
//
#include <hip/hip_runtime.h>

#define DD   256    // feature dim
#define CC   100    // num classes
#define TPB_ARG 192            // argmax: 3 waves
#define AW   3                 // accum waves per block
#define NBACC 256              // accum blocks (1 per CU)
#define TW   (NBACC * AW)      // total accum waves

typedef float f4 __attribute__((ext_vector_type(4)));

// Workspace layout (bytes):
//   [0, 102400)        : g_sums   (CC*DD f32, [c][comp][lane] permuted layout)
//   [102400, 102800)   : g_counts (CC int)
//   [102800, 103200)   : g_ssqc   (CC f32; only [0] accumulated here)
//   [103424, +4N)      : cls      (N int)
#define WS_SUMS_OFF   0
#define WS_COUNTS_OFF (CC * DD * 4)
#define WS_SSQC_OFF   (WS_COUNTS_OFF + CC * 4)
#define WS_HDR        (WS_SSQC_OFF + CC * 4)
#define WS_CLS_OFF    103424

// ---------------- kernel A: argmax via DMA-staged LDS tiles -----------------
// (r10/r17 structure — proven ~15-20 µs @ 5-6.7 TB/s) Wave-private 2x25.6KB
// LDS ping-pong, 25x global_load_lds w16 per 64-row tile, counted vmcnt,
// per-lane row argmax, cls[] store + LDS histogram -> g_counts.
__global__ __launch_bounds__(TPB_ARG) void k_argmax(
        const float* __restrict__ labels,
        int*   __restrict__ cls,
        int*   __restrict__ g_counts,
        int N)
{
    __shared__ f4  stage[3][2][1600];    // 3 waves x 2 bufs x 25600 B = 150 KB
    __shared__ int s_cnt[CC];

    const int tid  = threadIdx.x;
    const int lane = tid & 63;
    const int wid  = tid >> 6;
    if (tid < CC) s_cnt[tid] = 0;
    __syncthreads();

    const int ntiles = N >> 6;
    const int S      = gridDim.x * 3;    // total waves

#define DMA(b_, t_) do {                                                      \
    const float* gbase = labels + (size_t)(t_) * 6400 + lane * 4;             \
    f4* lbase = &stage[wid][b_][0];                                           \
    _Pragma("unroll")                                                         \
    for (int i_ = 0; i_ < 25; ++i_)                                           \
        __builtin_amdgcn_global_load_lds(                                     \
            (const __attribute__((address_space(1))) unsigned int*)(gbase + i_ * 256), \
            (__attribute__((address_space(3))) unsigned int*)(lbase + i_ * 64),       \
            16, 0, 0);                                                        \
} while (0)

#define CONSUME(b_, t_) do {                                                  \
    const f4* row_ = &stage[wid][b_][lane * 25];                              \
    f4 q0_ = row_[0];                                                         \
    float best_ = q0_[0]; int bi_ = 0;                                        \
    if (q0_[1] > best_) { best_ = q0_[1]; bi_ = 1; }                          \
    if (q0_[2] > best_) { best_ = q0_[2]; bi_ = 2; }                          \
    if (q0_[3] > best_) { best_ = q0_[3]; bi_ = 3; }                          \
    _Pragma("unroll")                                                         \
    for (int j_ = 1; j_ < 25; ++j_) {                                         \
        f4 q_ = row_[j_];                                                     \
        if (q_[0] > best_) { best_ = q_[0]; bi_ = 4 * j_; }                   \
        if (q_[1] > best_) { best_ = q_[1]; bi_ = 4 * j_ + 1; }               \
        if (q_[2] > best_) { best_ = q_[2]; bi_ = 4 * j_ + 2; }               \
        if (q_[3] > best_) { best_ = q_[3]; bi_ = 4 * j_ + 3; }               \
    }                                                                         \
    cls[(size_t)(t_) * 64 + lane] = bi_;                                      \
    atomicAdd(&s_cnt[bi_], 1);                                                \
} while (0)

    int t = blockIdx.x * 3 + wid;
    if (t < ntiles) {
        DMA(0, t);
        int cur = 0;
        int tn  = t + S;
        while (tn < ntiles) {
            DMA(cur ^ 1, tn);                         // prefetch next tile
            asm volatile("s_waitcnt vmcnt(25)" ::: "memory");  // cur tile ready
            __builtin_amdgcn_sched_barrier(0);
            CONSUME(cur, t);
            cur ^= 1; t = tn; tn += S;
        }
        asm volatile("s_waitcnt vmcnt(0)" ::: "memory");
        __builtin_amdgcn_sched_barrier(0);
        CONSUME(cur, t);
    }
#undef DMA
#undef CONSUME

    // tail rows (N % 64 != 0)
    if (blockIdx.x == 0 && wid == 0) {
        const int row = (ntiles << 6) + lane;
        if (row < N) {
            const float* lr = labels + (size_t)row * CC;
            float best = lr[0]; int bi = 0;
            for (int j = 1; j < CC; ++j)
                if (lr[j] > best) { best = lr[j]; bi = j; }
            cls[row] = bi;
            atomicAdd(&s_cnt[bi], 1);
        }
    }

    __syncthreads();
    if (tid < CC) {
        const int c = s_cnt[tid];
        if (c) atomicAdd(&g_counts[tid], c);
    }
}

// ---------------- kernel B: SEQUENTIAL DMA-streamed class-sum accumulate ----
// argmax-skeleton port. Per wave: grid-stride over 64-row windows (64KB
// sequential chunks -> full DRAM page efficiency, vs gather's 3.3 TB/s cap).
// Ring = 2 groups x 8 rows (16KB/wave in flight), vmcnt(8) ping-pong, ONE
// lgkmcnt(0) per 8-row group (r17 died on per-row drains with a 3-row ring).
// Consume per row: 1 lane-contiguous ds_read_b128 (conflict-free) + readlane
// class + 4 ds_add_f32 into [c][comp][lane] tile (bank=lane%32, free 2-way).
__global__ __launch_bounds__(AW * 64) void k_accum(
        const float* __restrict__ feats,
        const int*   __restrict__ cls,
        float* __restrict__ g_sums,
        float* __restrict__ g_ssqc,
        int N)
{
    __shared__ float s_sums[CC * DD];            // 100 KB, [c*256+comp*64+lane]
    __shared__ f4    ring[AW][16][64];           // 3 waves x 16 rows x 1KB = 48KB

    const int tid  = threadIdx.x;
    const int lane = tid & 63;
    const int wid  = tid >> 6;

    for (int i = tid; i < CC * DD; i += AW * 64) s_sums[i] = 0.f;
    __syncthreads();

    const int wave_id = blockIdx.x * AW + wid;
    const int nwin = (N + 63) >> 6;
    float ssq = 0.f;

// DMA one 8-row group into ring slot s_ (rows w*64 + g_*8 + 0..7, clamped).
#define DMAG(s_, w_, g_) do {                                                 \
    _Pragma("unroll")                                                         \
    for (int r_ = 0; r_ < 8; ++r_) {                                          \
        int row_ = (w_) * 64 + (g_) * 8 + r_;                                 \
        if (row_ >= N) row_ = N - 1;                                          \
        const float* g__ = feats + (size_t)row_ * DD + lane * 4;              \
        __builtin_amdgcn_global_load_lds(                                     \
            (const __attribute__((address_space(1))) unsigned int*)g__,       \
            (__attribute__((address_space(3))) unsigned int*)&ring[wid][(s_) * 8 + r_][0], \
            16, 0, 0);                                                        \
    }                                                                         \
} while (0)

// Consume one 8-row group from ring slot s_.
#define CONSG(s_, w_, g_) do {                                                \
    _Pragma("unroll")                                                         \
    for (int r_ = 0; r_ < 8; ++r_) {                                          \
        const int row_ = (w_) * 64 + (g_) * 8 + r_;                           \
        if (row_ < N) {                    /* wave-uniform guard */           \
            const f4 v_ = ring[wid][(s_) * 8 + r_][lane];                     \
            const int c_ = __builtin_amdgcn_readlane(c64, (g_) * 8 + r_);     \
            float* dst_ = &s_sums[c_ * DD + lane];                            \
            unsafeAtomicAdd(dst_ +   0, v_[0]);   /* ds_add_f32, bank free */ \
            unsafeAtomicAdd(dst_ +  64, v_[1]);                               \
            unsafeAtomicAdd(dst_ + 128, v_[2]);                               \
            unsafeAtomicAdd(dst_ + 192, v_[3]);                               \
            ssq += v_[0] * v_[0] + v_[1] * v_[1]                              \
                 + v_[2] * v_[2] + v_[3] * v_[3];                             \
        }                                                                     \
    }                                                                         \
} while (0)

#define WAITV(n_)  do { asm volatile("s_waitcnt vmcnt(" #n_ ")" ::: "memory"); \
                        __builtin_amdgcn_sched_barrier(0); } while (0)
#define DRAINL()   do { asm volatile("s_waitcnt lgkmcnt(0)" ::: "memory");     \
                        __builtin_amdgcn_sched_barrier(0); } while (0)

    for (int w = wave_id; w < nwin; w += TW) {
        // classes for this window (issued FIRST -> oldest in vmcnt queue)
        int crow = w * 64 + lane;
        if (crow >= N) crow = N - 1;
        const int c64 = cls[crow];
        __builtin_amdgcn_sched_barrier(0);

        DMAG(0, w, 0);                    // outstanding: cls + 8
        DMAG(1, w, 1);                    // outstanding: cls + 16
        WAITV(8);                         // cls + g0 landed
        CONSG(0, w, 0); DRAINL(); DMAG(0, w, 2);
        WAITV(8);                         // g1 landed
        CONSG(1, w, 1); DRAINL(); DMAG(1, w, 3);
        WAITV(8);
        CONSG(0, w, 2); DRAINL(); DMAG(0, w, 4);
        WAITV(8);
        CONSG(1, w, 3); DRAINL(); DMAG(1, w, 5);
        WAITV(8);
        CONSG(0, w, 4); DRAINL(); DMAG(0, w, 6);
        WAITV(8);
        CONSG(1, w, 5); DRAINL(); DMAG(1, w, 7);
        WAITV(8);
        CONSG(0, w, 6);
        WAITV(0);                         // g7 landed; window drained
        CONSG(1, w, 7);
    }
#undef DMAG
#undef CONSG
#undef WAITV
#undef DRAINL

    // ssq: wave reduce -> one fire-and-forget f32 atomic per wave
    #pragma unroll
    for (int off = 1; off < 64; off <<= 1) ssq += __shfl_xor(ssq, off);
    if (lane == 0) unsafeAtomicAdd(&g_ssqc[0], ssq);

    __syncthreads();                      // all waves' ds_adds complete
    // flush class-sum tile (permuted layout preserved globally)
    for (int i = tid; i < CC * DD; i += AW * 64) {
        const float s = s_sums[i];
        if (s != 0.f) unsafeAtomicAdd(&g_sums[i], s);
    }
}

// ---------------- finalize ---------------------------------------------------
// Layout-transparent: thread d owns one POSITION (a fixed permutation of the
// dim axis, identical across all blocks); all loss terms are sums over
// (class, position) and colmean is per-position -> permutation-invariant.
__global__ __launch_bounds__(DD) void affinity_finalize(
        const float* __restrict__ g_sums,
        const int*   __restrict__ g_counts,
        const float* __restrict__ g_ssqc,
        float* __restrict__ out)
{
    const int d = threadIdx.x;
    __shared__ int s_cnt[CC];
    if (d < CC) s_cnt[d] = g_counts[d];
    __syncthreads();

    double colsum = 0.0, s2 = 0.0, dot = 0.0, cc2 = 0.0;
    for (int cb = 0; cb < CC; cb += 4) {         // CC % 4 == 0
        float s[4];
        #pragma unroll
        for (int k = 0; k < 4; ++k)              // 4 independent loads
            s[k] = g_sums[(size_t)(cb + k) * DD + d];
        #pragma unroll
        for (int k = 0; k < 4; ++k) {
            const int    c  = s_cnt[cb + k];
            const double ce = (c > 0 ? (double)s[k] / (double)c : 0.0) + 1e-6;
            colsum += ce;
            s2     += ce * ce;
            dot    += ce * (double)s[k];
            cc2    += (double)c * ce * ce;
        }
    }
    double interp = s2 - colsum * colsum / (double)CC;

    __shared__ double red0[DD], red1[DD], red2[DD], red3[DD];
    red0[d] = dot; red1[d] = cc2; red2[d] = interp;
    red3[d] = (d < CC) ? (double)g_ssqc[d] : 0.0;
    __syncthreads();
    for (int off = DD / 2; off > 0; off >>= 1) {
        if (d < off) {
            red0[d] += red0[d + off];
            red1[d] += red1[d + off];
            red2[d] += red2[d + off];
            red3[d] += red3[d + off];
        }
        __syncthreads();
    }
    if (d == 0) {
        const double intra = red3[0] - 2.0 * red0[0] + red1[0];
        const double inter = red2[0] / (double)CC;
        out[0] = (float)(intra / (inter + 1e-6));
    }
}

extern "C" void kernel_launch(void* const* d_in, const int* in_sizes, int n_in,
                              void* d_out, int out_size, void* d_ws, size_t ws_size,
                              hipStream_t stream)
{
    const float* feats  = (const float*)d_in[0];
    const float* labels = (const float*)d_in[1];
    const int N = in_sizes[0] / DD;

    float* g_sums   = (float*)((char*)d_ws + WS_SUMS_OFF);
    int*   g_counts = (int*)((char*)d_ws + WS_COUNTS_OFF);
    float* g_ssqc   = (float*)((char*)d_ws + WS_SSQC_OFF);
    int*   cls      = (int*)((char*)d_ws + WS_CLS_OFF);

    hipMemsetAsync(d_ws, 0, WS_HDR, stream);     // zero sums/counts/ssqc

    k_argmax<<<256, TPB_ARG, 0, stream>>>(labels, cls, g_counts, N);

    k_accum<<<NBACC, AW * 64, 0, stream>>>(feats, cls, g_sums, g_ssqc, N);

    affinity_finalize<<<1, DD, 0, stream>>>(g_sums, g_counts, g_ssqc,
                                            (float*)d_out);
}